// Round 6
// baseline (406.012 us; speedup 1.0000x reference)
//
#include <hip/hip_runtime.h>

// TripletAngularMarginLoss: bs=16384, d=64 (== number of classes)
// out = mean(relu(0.5 + ap - an)) + mean(relu(0.8-ap)) + mean(relu(an-0.4)) + CE
// where ap[i] = min_{t[j]==t[i]} cos(x_i,x_j), an[i] = max_{t[j]!=t[i]} cos(x_i,x_j)

#define N_ROWS 16384
#define N_DIM 64

typedef __attribute__((ext_vector_type(8))) short bf16x8;
typedef __attribute__((ext_vector_type(4))) float f32x4;

__device__ inline unsigned short f2bf(float f) {
  unsigned u = __float_as_uint(f);
  unsigned r = u + 0x7fffu + ((u >> 16) & 1u);   // round-to-nearest-even
  return (unsigned short)(r >> 16);
}

// order-preserving float->uint encoding for atomicMin/atomicMax
__device__ inline unsigned enc_key(float f) {
  unsigned u = __float_as_uint(f);
  return (u & 0x80000000u) ? ~u : (u | 0x80000000u);
}
__device__ inline float dec_key(unsigned k) {
  unsigned u = (k & 0x80000000u) ? (k ^ 0x80000000u) : ~k;
  return __uint_as_float(u);
}

// async global->LDS DMA, 16B per lane, dest = lds_base + lane*16 (linear)
__device__ inline void g2lds16(const void* g, void* l) {
  __builtin_amdgcn_global_load_lds(
      (const __attribute__((address_space(1))) void*)g,
      (__attribute__((address_space(3))) void*)l, 16, 0, 0);
}

// ---------------- Kernel A: normalize rows, emit bf16 copy, per-row CE -------
// Also initializes the min/max key arrays and zeroes the output accumulator.
__global__ void prep_kernel(const float* __restrict__ x, const int* __restrict__ tgt,
                            unsigned short* __restrict__ xb, float* __restrict__ ce_row,
                            unsigned* __restrict__ mp_key, unsigned* __restrict__ mn_key,
                            float* __restrict__ out) {
  const int row  = blockIdx.x * 4 + (threadIdx.x >> 6);
  const int lane = threadIdx.x & 63;
  float v  = x[row * N_DIM + lane];
  float ss = v * v;
#pragma unroll
  for (int s = 1; s < 64; s <<= 1) ss += __shfl_xor(ss, s, 64);
  float xn = v * rsqrtf(ss);
  xb[row * N_DIM + lane] = f2bf(xn);

  // log-softmax over the 64 normalized features
  float mx = xn;
#pragma unroll
  for (int s = 1; s < 64; s <<= 1) mx = fmaxf(mx, __shfl_xor(mx, s, 64));
  float e  = __expf(xn - mx);
  float se = e;
#pragma unroll
  for (int s = 1; s < 64; s <<= 1) se += __shfl_xor(se, s, 64);
  float lse = mx + __logf(se);
  int   t   = tgt[row];                 // wave-uniform
  float xt  = __shfl(xn, t, 64);
  if (lane == 0) {
    ce_row[row] = lse - xt;
    mp_key[row] = 0xFFFFFFFFu;          // +inf key for atomicMin
    mn_key[row] = 0u;                   // -inf key for atomicMax
  }
  if (blockIdx.x == 0 && threadIdx.x == 0) out[0] = 0.f;
}

// ---------------- Kernel B: MFMA similarity tiles + hard mining --------------
// R4 post-mortem: time invariant (~108us) across FOUR codegen variants while
// occupancy doubled -> NOT issue/spill-bound. Derived counters are ~3x
// inflated (gfx94x fallback formulas): real VALU issue ~23us. The invariant
// is structural: one __syncthreads per jc (64/block) draining vmcnt(0) on a
// DMA issued ~150cy earlier -> every iteration eats full L2->LDS latency.
// Fix (T3-minimum): phase = 4 tiles staged at once (all 4 waves DMA one tile
// each, double-buffered), 4 jc computed per phase with no interior barrier,
// one vmcnt-drain+barrier per phase. Barriers 64 -> 16; each DMA gets a
// 4-iteration (~600cy) completion window.
// LDS = 2*4*2KB Bt + 2KB tjl = 18KB -> still 8 blocks/CU.
__global__ __launch_bounds__(256, 8)
void mine_kernel(const unsigned short* __restrict__ xb, const int* __restrict__ tgt,
                 unsigned* __restrict__ mp_key, unsigned* __restrict__ mn_key) {
  __shared__ unsigned short Bt[2][4][1024];  // 2 bufs x 4 tiles x 2KB, swizzled
  __shared__ unsigned short tjl[N_ROWS / 16]; // 2KB: targets of this j-range

  const int lane    = threadIdx.x & 63;
  const int wv      = threadIdx.x >> 6;
  const int iblk    = blockIdx.x >> 4;
  const int jspl    = blockIdx.x & 15;
  const int rowbase = iblk * 128 + wv * 32;
  const int m = lane & 15, q = lane >> 4;
  const int jbase = jspl * (N_ROWS / 16);

  // A fragments: lane holds row (rowbase+tr*16+m), k = q*8..q*8+7 (+32 for ks=1)
  bf16x8 a[2][2];
#pragma unroll
  for (int tr = 0; tr < 2; ++tr) {
    const unsigned short* p = xb + (rowbase + tr * 16 + m) * N_DIM + q * 8;
    a[tr][0] = *(const bf16x8*)(p);
    a[tr][1] = *(const bf16x8*)(p + 32);
  }
  // row targets for the C/D rows this lane owns: row = tr*16 + q*4 + r
  int ti[2][4];
#pragma unroll
  for (int tr = 0; tr < 2; ++tr)
#pragma unroll
    for (int r = 0; r < 4; ++r)
      ti[tr][r] = tgt[rowbase + tr * 16 + q * 4 + r];

  float mp[8], mn[8];
#pragma unroll
  for (int k = 0; k < 8; ++k) { mp[k] = __builtin_inff(); mn[k] = -__builtin_inff(); }

  // preload j-range targets into LDS (ds_read_u16 per jc, 2-way alias = free)
  for (int k = threadIdx.x; k < N_ROWS / 16; k += 256)
    tjl[k] = (unsigned short)tgt[jbase + k];

  // Staging (inverse-swizzled global source, linear LDS dest):
  // wave wv stages tile jc = ph*4+wv; call c in {0,1} covers cols c*8+(lane>>3),
  // dim-granule (lane&7)^((lane>>3)&7). Read side XORs granule by (col&7).
  const unsigned short* src0 =
      xb + (jbase + (lane >> 3)) * N_DIM + (((lane & 7) ^ ((lane >> 3) & 7)) * 8);
  // per-call extra col offset: c*8 columns = c*8*N_DIM shorts

  // prologue: stage phase 0 (tiles 0..3) into buffer 0
  {
    const unsigned short* s = src0 + (wv * 16) * N_DIM;
    g2lds16(s,             (unsigned short*)&Bt[0][wv][0] + lane * 8);         // c=0
    g2lds16(s + 8 * N_DIM, (unsigned short*)&Bt[0][wv][0] + 512 + lane * 8);   // c=1
  }
  __syncthreads();

  // swizzled fragment-read byte offsets (constant per lane):
  const int roff0 = m * 128 + ((q * 16) ^ ((m & 7) << 4));
  const int roff1 = m * 128 + (((64) + q * 16) ^ ((m & 7) << 4));

  for (int ph = 0; ph < 16; ++ph) {
    const int pb = ph & 1;
    if (ph < 15) {                      // stage phase ph+1 into the other buffer
      const unsigned short* s = src0 + ((ph + 1) * 64 + wv * 16) * N_DIM;
      g2lds16(s,             (unsigned short*)&Bt[pb ^ 1][wv][0] + lane * 8);
      g2lds16(s + 8 * N_DIM, (unsigned short*)&Bt[pb ^ 1][wv][0] + 512 + lane * 8);
    }
#pragma unroll
    for (int j4 = 0; j4 < 4; ++j4) {
      const int jc = ph * 4 + j4;
      const char* bb = (const char*)&Bt[pb][j4][0];
      const bf16x8 cb0 = *(const bf16x8*)(bb + roff0);
      const bf16x8 cb1 = *(const bf16x8*)(bb + roff1);
      const int    ctj = tjl[jc * 16 + m];

#pragma unroll
      for (int tr = 0; tr < 2; ++tr) {
        f32x4 acc = {0.f, 0.f, 0.f, 0.f};
        acc = __builtin_amdgcn_mfma_f32_16x16x32_bf16(a[tr][0], cb0, acc, 0, 0, 0);
        acc = __builtin_amdgcn_mfma_f32_16x16x32_bf16(a[tr][1], cb1, acc, 0, 0, 0);
#pragma unroll
        for (int r = 0; r < 4; ++r) {
          const bool  pos = (ctj == ti[tr][r]);
          const float d   = acc[r];
          const int   k   = tr * 4 + r;
          mp[k] = fminf(mp[k], pos ? d : __builtin_inff());
          mn[k] = fmaxf(mn[k], pos ? -__builtin_inff() : d);
        }
      }
    }
    __syncthreads();   // one vmcnt-drain + barrier per 4-tile phase
  }

  // reduce across the 16 lanes (m = 0..15) inside each q-group
#pragma unroll
  for (int s = 1; s < 16; s <<= 1) {
#pragma unroll
    for (int k = 0; k < 8; ++k) {
      mp[k] = fminf(mp[k], __shfl_xor(mp[k], s, 64));
      mn[k] = fmaxf(mn[k], __shfl_xor(mn[k], s, 64));
    }
  }
  if (m == 0) {
#pragma unroll
    for (int tr = 0; tr < 2; ++tr)
#pragma unroll
      for (int r = 0; r < 4; ++r) {
        const int row = rowbase + tr * 16 + q * 4 + r;
        atomicMin(&mp_key[row], enc_key(mp[tr * 4 + r]));
        atomicMax(&mn_key[row], enc_key(mn[tr * 4 + r]));
      }
  }
}

// ---------------- Kernel C: final reduction (8 blocks, float atomicAdd) ------
__global__ void finalize_kernel(const unsigned* __restrict__ mp_key, const unsigned* __restrict__ mn_key,
                                const float* __restrict__ ce_row, float* __restrict__ out) {
  __shared__ float red[16];
  float s = 0.f;
#pragma unroll
  for (int it = 0; it < 2; ++it) {
    const int r = it * 8192 + blockIdx.x * 1024 + threadIdx.x;
    float ap = dec_key(mp_key[r]);
    float an = dec_key(mn_key[r]);
    s += fmaxf(0.5f + ap - an, 0.f) + fmaxf(0.8f - ap, 0.f) +
         fmaxf(an - 0.4f, 0.f) + ce_row[r];
  }
#pragma unroll
  for (int sh = 1; sh < 64; sh <<= 1) s += __shfl_xor(s, sh, 64);
  const int wv = threadIdx.x >> 6;
  if ((threadIdx.x & 63) == 0) red[wv] = s;
  __syncthreads();
  if (threadIdx.x == 0) {
    float t = 0.f;
#pragma unroll
    for (int w = 0; w < 16; ++w) t += red[w];
    atomicAdd(out, t * (1.0f / N_ROWS));
  }
}

extern "C" void kernel_launch(void* const* d_in, const int* in_sizes, int n_in,
                              void* d_out, int out_size, void* d_ws, size_t ws_size,
                              hipStream_t stream) {
  const float* x   = (const float*)d_in[0];
  const int*   tgt = (const int*)d_in[1];
  char* ws = (char*)d_ws;

  unsigned short* xb     = (unsigned short*)ws;                          // 2 MB bf16 normalized
  unsigned*       mp_key = (unsigned*)(ws + (2u << 20));                 // 64 KB
  unsigned*       mn_key = (unsigned*)(ws + (2u << 20) + (64u << 10));   // 64 KB
  float*          ce_row = (float*)(ws + (2u << 20) + (128u << 10));     // 64 KB
  float*          out    = (float*)d_out;

  prep_kernel<<<N_ROWS / 4, 256, 0, stream>>>(x, tgt, xb, ce_row, mp_key, mn_key, out);
  mine_kernel<<<(N_ROWS / 128) * 16, 256, 0, stream>>>(xb, tgt, mp_key, mn_key);
  finalize_kernel<<<8, 1024, 0, stream>>>(mp_key, mn_key, ce_row, out);
}

// Round 7
// 156.390 us; speedup vs baseline: 2.5961x; 2.5961x over previous
//
#include <hip/hip_runtime.h>

// TripletAngularMarginLoss: bs=16384, d=64 (== number of classes)
// out = mean(relu(0.5 + ap - an)) + mean(relu(0.8-ap)) + mean(relu(an-0.4)) + CE
// where ap[i] = min_{t[j]==t[i]} cos(x_i,x_j), an[i] = max_{t[j]!=t[i]} cos(x_i,x_j)

#define N_ROWS 16384
#define N_DIM 64

typedef __attribute__((ext_vector_type(8))) short bf16x8;
typedef __attribute__((ext_vector_type(4))) float f32x4;

__device__ inline unsigned short f2bf(float f) {
  unsigned u = __float_as_uint(f);
  unsigned r = u + 0x7fffu + ((u >> 16) & 1u);   // round-to-nearest-even
  return (unsigned short)(r >> 16);
}

// order-preserving float->uint encoding for atomicMin/atomicMax
__device__ inline unsigned enc_key(float f) {
  unsigned u = __float_as_uint(f);
  return (u & 0x80000000u) ? ~u : (u | 0x80000000u);
}
__device__ inline float dec_key(unsigned k) {
  unsigned u = (k & 0x80000000u) ? (k ^ 0x80000000u) : ~k;
  return __uint_as_float(u);
}

// async global->LDS DMA, 16B per lane, dest = lds_base + lane*16 (linear)
__device__ inline void g2lds16(const void* g, void* l) {
  __builtin_amdgcn_global_load_lds(
      (const __attribute__((address_space(1))) void*)g,
      (__attribute__((address_space(3))) void*)l, 16, 0, 0);
}

// ---------------- Kernel A: normalize rows, emit bf16 copy, per-row CE -------
// Also initializes the min/max key arrays and zeroes the output accumulator.
__global__ void prep_kernel(const float* __restrict__ x, const int* __restrict__ tgt,
                            unsigned short* __restrict__ xb, float* __restrict__ ce_row,
                            unsigned* __restrict__ mp_key, unsigned* __restrict__ mn_key,
                            float* __restrict__ out) {
  const int row  = blockIdx.x * 4 + (threadIdx.x >> 6);
  const int lane = threadIdx.x & 63;
  float v  = x[row * N_DIM + lane];
  float ss = v * v;
#pragma unroll
  for (int s = 1; s < 64; s <<= 1) ss += __shfl_xor(ss, s, 64);
  float xn = v * rsqrtf(ss);
  xb[row * N_DIM + lane] = f2bf(xn);

  // log-softmax over the 64 normalized features
  float mx = xn;
#pragma unroll
  for (int s = 1; s < 64; s <<= 1) mx = fmaxf(mx, __shfl_xor(mx, s, 64));
  float e  = __expf(xn - mx);
  float se = e;
#pragma unroll
  for (int s = 1; s < 64; s <<= 1) se += __shfl_xor(se, s, 64);
  float lse = mx + __logf(se);
  int   t   = tgt[row];                 // wave-uniform
  float xt  = __shfl(xn, t, 64);
  if (lane == 0) {
    ce_row[row] = lse - xt;
    mp_key[row] = 0xFFFFFFFFu;          // +inf key for atomicMin
    mn_key[row] = 0u;                   // -inf key for atomicMax
  }
  if (blockIdx.x == 0 && threadIdx.x == 0) out[0] = 0.f;
}

// ---------------- Kernel B: MFMA similarity tiles + hard mining --------------
// R6 post-mortem: 4-tile phases + full j4 unroll -> mp/mn spilled PER PHASE
// (FETCH 663MB / WRITE 1GB, HBM 62%, 344us). The unroll (not the phase
// structure) drove pressure past the 32-VGPR allocation. R7: identical phase
// structure but '#pragma unroll 1' on j4 so in-flight pressure stays at R4's
// level (mp/mn resident), isolating the barrier variable: barriers/drains
// 64 -> 16 per block, each DMA gets a ~600cy completion window.
// LDS = 2*4*2KB Bt + 2KB tjl = 18KB -> 8 blocks/CU.
__global__ __launch_bounds__(256, 8)
void mine_kernel(const unsigned short* __restrict__ xb, const int* __restrict__ tgt,
                 unsigned* __restrict__ mp_key, unsigned* __restrict__ mn_key) {
  __shared__ unsigned short Bt[2][4][1024];  // 2 bufs x 4 tiles x 2KB, swizzled
  __shared__ unsigned short tjl[N_ROWS / 16]; // 2KB: targets of this j-range

  const int lane    = threadIdx.x & 63;
  const int wv      = threadIdx.x >> 6;
  const int iblk    = blockIdx.x >> 4;
  const int jspl    = blockIdx.x & 15;
  const int rowbase = iblk * 128 + wv * 32;
  const int m = lane & 15, q = lane >> 4;
  const int jbase = jspl * (N_ROWS / 16);

  // A fragments: lane holds row (rowbase+tr*16+m), k = q*8..q*8+7 (+32 for ks=1)
  bf16x8 a[2][2];
#pragma unroll
  for (int tr = 0; tr < 2; ++tr) {
    const unsigned short* p = xb + (rowbase + tr * 16 + m) * N_DIM + q * 8;
    a[tr][0] = *(const bf16x8*)(p);
    a[tr][1] = *(const bf16x8*)(p + 32);
  }
  // row targets for the C/D rows this lane owns: row = tr*16 + q*4 + r
  int ti[2][4];
#pragma unroll
  for (int tr = 0; tr < 2; ++tr)
#pragma unroll
    for (int r = 0; r < 4; ++r)
      ti[tr][r] = tgt[rowbase + tr * 16 + q * 4 + r];

  float mp[8], mn[8];
#pragma unroll
  for (int k = 0; k < 8; ++k) { mp[k] = __builtin_inff(); mn[k] = -__builtin_inff(); }

  // preload j-range targets into LDS (ds_read_u16 per jc, 2-way alias = free)
  for (int k = threadIdx.x; k < N_ROWS / 16; k += 256)
    tjl[k] = (unsigned short)tgt[jbase + k];

  // Staging (inverse-swizzled global source, linear LDS dest):
  // wave wv stages tile jc = ph*4+wv; call c in {0,1} covers cols c*8+(lane>>3),
  // dim-granule (lane&7)^((lane>>3)&7). Read side XORs granule by (col&7).
  const unsigned short* src0 =
      xb + (jbase + (lane >> 3)) * N_DIM + (((lane & 7) ^ ((lane >> 3) & 7)) * 8);

  // prologue: stage phase 0 (tiles 0..3) into buffer 0
  {
    const unsigned short* s = src0 + (wv * 16) * N_DIM;
    g2lds16(s,             (unsigned short*)&Bt[0][wv][0] + lane * 8);         // c=0
    g2lds16(s + 8 * N_DIM, (unsigned short*)&Bt[0][wv][0] + 512 + lane * 8);   // c=1
  }
  __syncthreads();

  // swizzled fragment-read byte offsets (constant per lane):
  const int roff0 = m * 128 + ((q * 16) ^ ((m & 7) << 4));
  const int roff1 = m * 128 + (((64) + q * 16) ^ ((m & 7) << 4));

  for (int ph = 0; ph < 16; ++ph) {
    const int pb = ph & 1;
    if (ph < 15) {                      // stage phase ph+1 into the other buffer
      const unsigned short* s = src0 + ((ph + 1) * 64 + wv * 16) * N_DIM;
      g2lds16(s,             (unsigned short*)&Bt[pb ^ 1][wv][0] + lane * 8);
      g2lds16(s + 8 * N_DIM, (unsigned short*)&Bt[pb ^ 1][wv][0] + 512 + lane * 8);
    }
#pragma unroll 1
    for (int j4 = 0; j4 < 4; ++j4) {
      const int jc = ph * 4 + j4;
      const char* bb = (const char*)&Bt[pb][j4][0];
      const bf16x8 cb0 = *(const bf16x8*)(bb + roff0);
      const bf16x8 cb1 = *(const bf16x8*)(bb + roff1);
      const int    ctj = tjl[jc * 16 + m];

#pragma unroll
      for (int tr = 0; tr < 2; ++tr) {
        f32x4 acc = {0.f, 0.f, 0.f, 0.f};
        acc = __builtin_amdgcn_mfma_f32_16x16x32_bf16(a[tr][0], cb0, acc, 0, 0, 0);
        acc = __builtin_amdgcn_mfma_f32_16x16x32_bf16(a[tr][1], cb1, acc, 0, 0, 0);
#pragma unroll
        for (int r = 0; r < 4; ++r) {
          const bool  pos = (ctj == ti[tr][r]);
          const float d   = acc[r];
          const int   k   = tr * 4 + r;
          mp[k] = fminf(mp[k], pos ? d : __builtin_inff());
          mn[k] = fmaxf(mn[k], pos ? -__builtin_inff() : d);
        }
      }
    }
    __syncthreads();   // one vmcnt-drain + barrier per 4-tile phase
  }

  // reduce across the 16 lanes (m = 0..15) inside each q-group
#pragma unroll
  for (int s = 1; s < 16; s <<= 1) {
#pragma unroll
    for (int k = 0; k < 8; ++k) {
      mp[k] = fminf(mp[k], __shfl_xor(mp[k], s, 64));
      mn[k] = fmaxf(mn[k], __shfl_xor(mn[k], s, 64));
    }
  }
  if (m == 0) {
#pragma unroll
    for (int tr = 0; tr < 2; ++tr)
#pragma unroll
      for (int r = 0; r < 4; ++r) {
        const int row = rowbase + tr * 16 + q * 4 + r;
        atomicMin(&mp_key[row], enc_key(mp[tr * 4 + r]));
        atomicMax(&mn_key[row], enc_key(mn[tr * 4 + r]));
      }
  }
}

// ---------------- Kernel C: final reduction (8 blocks, float atomicAdd) ------
__global__ void finalize_kernel(const unsigned* __restrict__ mp_key, const unsigned* __restrict__ mn_key,
                                const float* __restrict__ ce_row, float* __restrict__ out) {
  __shared__ float red[16];
  float s = 0.f;
#pragma unroll
  for (int it = 0; it < 2; ++it) {
    const int r = it * 8192 + blockIdx.x * 1024 + threadIdx.x;
    float ap = dec_key(mp_key[r]);
    float an = dec_key(mn_key[r]);
    s += fmaxf(0.5f + ap - an, 0.f) + fmaxf(0.8f - ap, 0.f) +
         fmaxf(an - 0.4f, 0.f) + ce_row[r];
  }
#pragma unroll
  for (int sh = 1; sh < 64; sh <<= 1) s += __shfl_xor(s, sh, 64);
  const int wv = threadIdx.x >> 6;
  if ((threadIdx.x & 63) == 0) red[wv] = s;
  __syncthreads();
  if (threadIdx.x == 0) {
    float t = 0.f;
#pragma unroll
    for (int w = 0; w < 16; ++w) t += red[w];
    atomicAdd(out, t * (1.0f / N_ROWS));
  }
}

extern "C" void kernel_launch(void* const* d_in, const int* in_sizes, int n_in,
                              void* d_out, int out_size, void* d_ws, size_t ws_size,
                              hipStream_t stream) {
  const float* x   = (const float*)d_in[0];
  const int*   tgt = (const int*)d_in[1];
  char* ws = (char*)d_ws;

  unsigned short* xb     = (unsigned short*)ws;                          // 2 MB bf16 normalized
  unsigned*       mp_key = (unsigned*)(ws + (2u << 20));                 // 64 KB
  unsigned*       mn_key = (unsigned*)(ws + (2u << 20) + (64u << 10));   // 64 KB
  float*          ce_row = (float*)(ws + (2u << 20) + (128u << 10));     // 64 KB
  float*          out    = (float*)d_out;

  prep_kernel<<<N_ROWS / 4, 256, 0, stream>>>(x, tgt, xb, ce_row, mp_key, mn_key, out);
  mine_kernel<<<(N_ROWS / 128) * 16, 256, 0, stream>>>(xb, tgt, mp_key, mn_key);
  finalize_kernel<<<8, 1024, 0, stream>>>(mp_key, mn_key, ce_row, out);
}